// Round 5
// baseline (142.327 us; speedup 1.0000x reference)
//
#include <hip/hip_runtime.h>

#define DEVFN static __device__ __forceinline__

constexpr int kLtot = 1024, kC = 32, kB = 2;
constexpr int kG = 64;                 // chunks per chain
constexpr int kCL = kLtot / kG;        // 16 steps per chunk
constexpr int kHL = kCL / 2;           // 8 steps per half-chunk (one wave each)
constexpr int kNCH = kB * kC;          // 64 chains
constexpr int kNCK = kNCH * kG;        // 4096 chunks

// per-wave LDS: two 2048B A-slots (DMA ring) + 2448B pbuf (P bounce rows + v row).
// pbuf doubles post-loop as the half-product exchange buffer (planes at 0/1024, v at 2304).
constexpr int kSlotB = 2048;
constexpr int kPbufB = 2448;
constexpr int kWaveB = 2 * kSlotB + kPbufB;  // 6544

typedef int v2i __attribute__((ext_vector_type(2)));

DEVFN void gload16(const void* g, void* l) {
  __builtin_amdgcn_global_load_lds((const __attribute__((address_space(1))) void*)g,
                                   (__attribute__((address_space(3))) void*)l, 16, 0, 0);
}

// xor-16 via ds_swizzle (DS pipe — overlaps VALU; R3-proven faster than permlane16_swap)
DEVFN float redpair16(float x) {
  return x + __int_as_float(__builtin_amdgcn_ds_swizzle(__float_as_int(x), 0x401F));
}
DEVFN float redpair32(float x) {
#if __has_builtin(__builtin_amdgcn_permlane32_swap)
  v2i r = __builtin_amdgcn_permlane32_swap(__float_as_int(x), __float_as_int(x), false, false);
  return __int_as_float(r.x) + __int_as_float(r.y);
#else
  return x + __shfl_xor(x, 32);
#endif
}
DEVFN float redq(float x) { return redpair32(redpair16(x)); }  // sum over 4 kq-partners

DEVFN float sel4(float x0, float x1, float x2, float x3, int b) {
  float lo = (b & 1) ? x1 : x0;
  float hi = (b & 1) ? x3 : x2;
  return (b & 2) ? hi : lo;
}

// ---------------- Phase 1: chunk transition P_g + response v_g (pair-wave) ----------------
// 2 waves per chunk: wave h builds the half-product over steps [t0+8h, t0+8h+8).
// Lane (kq,ka,kc): partials np[ka+4r][4kc+jj] over k in [4kq,4kq+4); redq over kq;
// p redistributed via per-wave LDS transpose bounce. After the loop, waveHi exports its
// half-product into its pbuf (A-tile plane layout) + vH; waveLo runs ONE more combine step
// (same machinery, tile := partner pbuf, x := vH) giving P_g, v_g.
__global__ __launch_bounds__(256, 6) void pscan_phase1(
    const float* __restrict__ Ar, const float* __restrict__ Ai,
    const float* __restrict__ Xr, const float* __restrict__ Xi,
    float* __restrict__ Pg, float* __restrict__ Vg) {
  __shared__ __align__(16) float ldsF[4 * (kWaveB / 4)];
  const int lane = threadIdx.x & 63;
  const int wid = threadIdx.x >> 6;
  const int kq = lane >> 4, ka = (lane >> 2) & 3, kc = lane & 3;
  const int jv = 4 * kc + ka;

  const int ck = blockIdx.x * 2 + (wid >> 1);
  const int h = wid & 1;
  const int chain = ck >> 6, g = ck & 63;
  const int bb = chain >> 5, cc = chain & 31;
  const int first = g * kCL + kHL * h;

  char* ldsW = (char*)ldsF + wid * kWaveB;
  char* pbase = ldsW + 2 * kSlotB;
  const int laneA = ka * 64 + kq * 16;
  const int laneAv = laneA + kc * 256;

  const size_t aBase = ((size_t)(bb * kLtot + first) * kC + cc) * 256;
  const size_t xBase = ((size_t)(bb * kLtot + first) * kC + cc) * 16;
  const float* arPtr = Ar + aBase + (size_t)lane * 4;
  const float* aiPtr = Ai + aBase + (size_t)lane * 4;
  const float* xrPtr = Xr + xBase + jv;
  const float* xiPtr = Xi + xBase + jv;

  char* wA = pbase + (ka + 4 * kq) * 144 + kc * 32;           // bounce write row ka+4kq, quad kc
  const char* rA = pbase + (4 * kq) * 144 + kc * 32;          // bounce read rows 4kq+kk
  char* vwA = pbase + 2304 + jv * 8;                          // v write (kq==0 lanes only)
  const char* vrA = pbase + 2304 + kq * 32;                   // v read slice

  float xrP[2], xiP[2];
  auto issueStep = [&](int sTile, int par) {                  // 4 vmem ops, always
    const size_t ao = (size_t)sTile * (kC * 256);
    char* sd = ldsW + par * kSlotB;
    gload16(arPtr + ao, sd);
    gload16(aiPtr + ao, sd + 1024);
    xrP[par] = xrPtr[(size_t)sTile * (kC * 16)];
    xiP[par] = xiPtr[(size_t)sTile * (kC * 16)];
  };

  issueStep(0, 0);
  asm volatile("" ::: "memory");
  issueStep(1, 1);
  asm volatile("" ::: "memory");

  float prk[4][4], pik[4][4];   // p[kk][jj] = P[4kq+kk][4kc+jj]
  float npr[4][4], npi[4][4];   // np[r][jj] = P_new[ka+4r][4kc+jj]
  float vre[4], vim[4];         // v[4kq+kk]
  float vnr = 0.f, vni = 0.f;

  // ---- init: P = A_first, v = x_first ----
  asm volatile("s_waitcnt vmcnt(4)" ::: "memory");
  {
    const char* sb = ldsW;
#pragma unroll
    for (int kk = 0; kk < 4; ++kk) {
      const float4 a4 = *(const float4*)(sb + (4 * kq + kk) * 64 + kc * 16);
      const float4 b4 = *(const float4*)(sb + 1024 + (4 * kq + kk) * 64 + kc * 16);
      prk[kk][0] = a4.x; prk[kk][1] = a4.y; prk[kk][2] = a4.z; prk[kk][3] = a4.w;
      pik[kk][0] = b4.x; pik[kk][1] = b4.y; pik[kk][2] = b4.z; pik[kk][3] = b4.w;
    }
    const float* xr0 = Xr + xBase;
    const float* xi0 = Xi + xBase;
#pragma unroll
    for (int kk = 0; kk < 4; ++kk) {
      vre[kk] = xr0[4 * kq + kk];
      vim[kk] = xi0[4 * kq + kk];
    }
  }
  asm volatile("s_waitcnt lgkmcnt(0)" ::: "memory");  // slot-0 reads done before re-staging
  issueStep(2, 0);
  asm volatile("" ::: "memory");

  auto stepCompute = [&](const char* sb, int par) {
    const char* sbl = sb + laneA;
#pragma unroll
    for (int r = 0; r < 4; ++r) {
      const float4 a4 = *(const float4*)(sbl + r * 256);
      const float4 b4 = *(const float4*)(sbl + 1024 + r * 256);
#pragma unroll
      for (int jj = 0; jj < 4; ++jj) {
        float nr = a4.x * prk[0][jj] - b4.x * pik[0][jj];
        float ni = a4.x * pik[0][jj] + b4.x * prk[0][jj];
        nr += a4.y * prk[1][jj] - b4.y * pik[1][jj];
        ni += a4.y * pik[1][jj] + b4.y * prk[1][jj];
        nr += a4.z * prk[2][jj] - b4.z * pik[2][jj];
        ni += a4.z * pik[2][jj] + b4.z * prk[2][jj];
        nr += a4.w * prk[3][jj] - b4.w * pik[3][jj];
        ni += a4.w * pik[3][jj] + b4.w * prk[3][jj];
        npr[r][jj] = nr; npi[r][jj] = ni;
      }
    }
    {  // v partial: row jv, own k-slice; x (or vH) added by caller via xrP/xiP[par]
      const float4 a4 = *(const float4*)(sb + laneAv);
      const float4 b4 = *(const float4*)(sb + laneAv + 1024);
      float pr = a4.x * vre[0] - b4.x * vim[0];
      float pi = a4.x * vim[0] + b4.x * vre[0];
      pr += a4.y * vre[1] - b4.y * vim[1];  pi += a4.y * vim[1] + b4.y * vre[1];
      pr += a4.z * vre[2] - b4.z * vim[2];  pi += a4.z * vim[2] + b4.z * vre[2];
      pr += a4.w * vre[3] - b4.w * vim[3];  pi += a4.w * vim[3] + b4.w * vre[3];
      pr = redq(pr); pi = redq(pi);
      vnr = pr + xrP[par];
      vni = pi + xiP[par];
    }
#pragma unroll
    for (int r = 0; r < 4; ++r)
#pragma unroll
      for (int jj = 0; jj < 4; ++jj) {
        npr[r][jj] = redq(npr[r][jj]);
        npi[r][jj] = redq(npi[r][jj]);
      }
  };

  auto stepBounce = [&]() {
#pragma unroll
    for (int u = 0; u < 2; ++u) {
      float4 w;
      w.x = sel4(npr[0][2 * u], npr[1][2 * u], npr[2][2 * u], npr[3][2 * u], kq);
      w.y = sel4(npi[0][2 * u], npi[1][2 * u], npi[2][2 * u], npi[3][2 * u], kq);
      w.z = sel4(npr[0][2 * u + 1], npr[1][2 * u + 1], npr[2][2 * u + 1], npr[3][2 * u + 1], kq);
      w.w = sel4(npi[0][2 * u + 1], npi[1][2 * u + 1], npi[2][2 * u + 1], npi[3][2 * u + 1], kq);
      *(float4*)(wA + u * 16) = w;
    }
    if (kq == 0) *(float2*)vwA = make_float2(vnr, vni);
    asm volatile("s_waitcnt lgkmcnt(0)" ::: "memory");
#pragma unroll
    for (int kk = 0; kk < 4; ++kk) {
      const float4 q0 = *(const float4*)(rA + kk * 144);
      const float4 q1 = *(const float4*)(rA + kk * 144 + 16);
      prk[kk][0] = q0.x; pik[kk][0] = q0.y; prk[kk][1] = q0.z; pik[kk][1] = q0.w;
      prk[kk][2] = q1.x; pik[kk][2] = q1.y; prk[kk][3] = q1.z; pik[kk][3] = q1.w;
    }
    const float4 v0 = *(const float4*)(vrA);
    const float4 v1 = *(const float4*)(vrA + 16);
    vre[0] = v0.x; vim[0] = v0.y; vre[1] = v0.z; vim[1] = v0.w;
    vre[2] = v1.x; vim[2] = v1.y; vre[3] = v1.z; vim[3] = v1.w;
  };

  // 7 half-chunk steps; uniform vmcnt(4) pattern with clamped (dummy) trailing issues
#pragma unroll 2
  for (int s = 1; s < kHL; ++s) {
    asm volatile("s_waitcnt vmcnt(4)" ::: "memory");
    stepCompute(ldsW + (s & 1) * kSlotB, s & 1);
    stepBounce();
    const int sn = s + 2;
    issueStep((sn < kHL) ? sn : (kHL - 1), sn & 1);
  }

  // ---- waveHi: export half-product (plane layout) + vH into own pbuf ----
  if (h == 1) {
    char* mb = pbase;
    float4 wre, wim;
    wre.x = sel4(prk[0][0], prk[1][0], prk[2][0], prk[3][0], ka);
    wre.y = sel4(prk[0][1], prk[1][1], prk[2][1], prk[3][1], ka);
    wre.z = sel4(prk[0][2], prk[1][2], prk[2][2], prk[3][2], ka);
    wre.w = sel4(prk[0][3], prk[1][3], prk[2][3], prk[3][3], ka);
    wim.x = sel4(pik[0][0], pik[1][0], pik[2][0], pik[3][0], ka);
    wim.y = sel4(pik[0][1], pik[1][1], pik[2][1], pik[3][1], ka);
    wim.z = sel4(pik[0][2], pik[1][2], pik[2][2], pik[3][2], ka);
    wim.w = sel4(pik[0][3], pik[1][3], pik[2][3], pik[3][3], ka);
    const int rowSel = 4 * kq + ka;
    *(float4*)(mb + rowSel * 64 + kc * 16) = wre;
    *(float4*)(mb + 1024 + rowSel * 64 + kc * 16) = wim;
    if (ka == 0 && kc == 0) {
      float4 v0; v0.x = vre[0]; v0.y = vim[0]; v0.z = vre[1]; v0.w = vim[1];
      float4 v1; v1.x = vre[2]; v1.y = vim[2]; v1.z = vre[3]; v1.w = vim[3];
      *(float4*)(mb + 2304 + kq * 32) = v0;
      *(float4*)(mb + 2304 + kq * 32 + 16) = v1;
    }
  }
  __syncthreads();

  // ---- waveLo: combine P_g = PH*PL, v_g = PH*vL + vH; store ----
  if (h == 0) {
    const char* mb = (char*)ldsF + (wid ^ 1) * kWaveB + 2 * kSlotB;
    const float2 vH = *(const float2*)(mb + 2304 + jv * 8);
    xrP[0] = vH.x; xiP[0] = vH.y;      // combine adds vH in place of x
    stepCompute(mb, 0);

    if (kq == 0) {
      float* pd = Pg + (size_t)ck * 512;
#pragma unroll
      for (int r = 0; r < 4; ++r) {
#pragma unroll
        for (int u = 0; u < 2; ++u) {
          float4 o;
          o.x = npr[r][2 * u];     o.y = npi[r][2 * u];
          o.z = npr[r][2 * u + 1]; o.w = npi[r][2 * u + 1];
          *(float4*)(pd + (ka + 4 * r) * 32 + 8 * kc + 4 * u) = o;
        }
      }
      *(float2*)(Vg + (size_t)ck * 32 + jv * 2) = make_float2(vnr, vni);
    }
  }
}

// ---------------- Phase 2: sequential carry scan (1 chain per wave, 64-lane matvec) ----------
constexpr int kD2 = 4;
__global__ __launch_bounds__(64, 1) void pscan_phase2(
    const float* __restrict__ Pg, const float* __restrict__ Vg, float* __restrict__ Sg) {
  const int lane = threadIdx.x;
  const int kq = lane >> 4, i = lane & 15;
  const int chain = blockIdx.x;

  const float* pB = Pg + (size_t)chain * kG * 512 + (size_t)i * 32 + 8 * kq;
  const float* vB = Vg + (size_t)chain * kG * 32 + 2 * i;
  float* sB = Sg + (size_t)chain * kG * 32 + 2 * i;

  float4 bP0[kD2], bP1[kD2]; float2 bV[kD2];
#pragma unroll
  for (int d = 0; d < kD2; ++d) {
    bP0[d] = *(const float4*)(pB + (size_t)d * 512);
    bP1[d] = *(const float4*)(pB + (size_t)d * 512 + 4);
    bV[d] = *(const float2*)(vB + (size_t)d * 32);
  }

  float ykr[4] = {0, 0, 0, 0}, yki[4] = {0, 0, 0, 0};  // y[4kq+kk]
  float ynr = 0.f, yni = 0.f;                          // own y[i]

  for (int gg = 0; gg < kG; gg += kD2) {
#pragma unroll
    for (int d = 0; d < kD2; ++d) {
      if (kq == 0) *(float2*)(sB + (size_t)(gg + d) * 32) = make_float2(ynr, yni);  // S_{g-1}
      const float4 p0 = bP0[d], p1 = bP1[d];
      const float2 vv = bV[d];
      const int gn = gg + d + kD2;
      if (gn < kG) {
        bP0[d] = *(const float4*)(pB + (size_t)gn * 512);
        bP1[d] = *(const float4*)(pB + (size_t)gn * 512 + 4);
        bV[d] = *(const float2*)(vB + (size_t)gn * 32);
      }
      float tr = p0.x * ykr[0] - p0.y * yki[0] + p0.z * ykr[1] - p0.w * yki[1]
               + p1.x * ykr[2] - p1.y * yki[2] + p1.z * ykr[3] - p1.w * yki[3];
      float ti = p0.x * yki[0] + p0.y * ykr[0] + p0.z * yki[1] + p0.w * ykr[1]
               + p1.x * yki[2] + p1.y * ykr[2] + p1.z * yki[3] + p1.w * ykr[3];
      tr = redq(tr); ti = redq(ti);
      ynr = tr + vv.x;
      yni = ti + vv.y;
#pragma unroll
      for (int kk = 0; kk < 4; ++kk) {
        const int src = (lane & 48) | (4 * kq + kk);
        ykr[kk] = __shfl(ynr, src);
        yki[kk] = __shfl(yni, src);
      }
    }
  }
}

// ---------------- Phase 3: replay chunks from carries (64-lane matvec, high occupancy) ----------
__global__ __launch_bounds__(256, 4) void pscan_phase3(
    const float* __restrict__ Ar, const float* __restrict__ Ai,
    const float* __restrict__ Xr, const float* __restrict__ Xi,
    const float* __restrict__ Sg, float* __restrict__ out) {
  const int lane = threadIdx.x & 63;
  const int wid = threadIdx.x >> 6;
  const int kq = lane >> 4, i = lane & 15;
  const int ck = blockIdx.x * 4 + wid;
  const int chain = ck >> 6, g = ck & 63;
  const int bb = chain >> 5, cc = chain & 31;
  const int t0 = g * kCL;

  const size_t aBase = ((size_t)(bb * kLtot + t0) * kC + cc) * 256 + (size_t)i * 16 + 4 * kq;
  const size_t xBase = ((size_t)(bb * kLtot + t0) * kC + cc) * 16 + i;
  const size_t aStep = (size_t)kC * 256, xStep = (size_t)kC * 16;
  float* outB = out + ((size_t)(bb * kLtot + t0) * kC + cc) * 32 + 2 * i;

  float ynr, yni, ykr[4], yki[4];
  {
    const float2 s = *(const float2*)(Sg + (size_t)ck * 32 + 2 * i);
    ynr = s.x; yni = s.y;
  }
#pragma unroll
  for (int kk = 0; kk < 4; ++kk) {
    const int src = (lane & 48) | (4 * kq + kk);
    ykr[kk] = __shfl(ynr, src);
    yki[kk] = __shfl(yni, src);
  }

  float4 aR[2], aI[2]; float2 xx[2];
  auto loadT = [&](int t, int s) {
    aR[s] = *(const float4*)(Ar + aBase + (size_t)t * aStep);
    aI[s] = *(const float4*)(Ai + aBase + (size_t)t * aStep);
    xx[s].x = Xr[xBase + (size_t)t * xStep];
    xx[s].y = Xi[xBase + (size_t)t * xStep];
  };
  loadT(0, 0);
  loadT(1, 1);

  for (int t = 0; t < kCL; ++t) {
    const int s = t & 1;
    const float4 a4 = aR[s], b4 = aI[s];
    const float2 xv = xx[s];
    float tr = a4.x * ykr[0] - b4.x * yki[0] + a4.y * ykr[1] - b4.y * yki[1]
             + a4.z * ykr[2] - b4.z * yki[2] + a4.w * ykr[3] - b4.w * yki[3];
    float ti = a4.x * yki[0] + b4.x * ykr[0] + a4.y * yki[1] + b4.y * ykr[1]
             + a4.z * yki[2] + b4.z * ykr[2] + a4.w * yki[3] + b4.w * ykr[3];
    tr = redq(tr); ti = redq(ti);
    ynr = tr + xv.x;
    yni = ti + xv.y;
    if (kq == 0) *(float2*)(outB + (size_t)t * (kC * 32)) = make_float2(ynr, yni);
    const int tn = t + 2;
    if (tn < kCL) loadT(tn, s);
#pragma unroll
    for (int kk = 0; kk < 4; ++kk) {
      const int src = (lane & 48) | (4 * kq + kk);
      ykr[kk] = __shfl(ynr, src);
      yki[kk] = __shfl(yni, src);
    }
  }
}

extern "C" void kernel_launch(void* const* d_in, const int* in_sizes, int n_in,
                              void* d_out, int out_size, void* d_ws, size_t ws_size,
                              hipStream_t stream) {
  const float* Ar = (const float*)d_in[0];
  const float* Ai = (const float*)d_in[1];
  const float* Xr = (const float*)d_in[2];
  const float* Xi = (const float*)d_in[3];
  // Workspace: Pg 8MB + Vg 512KB + Sg 512KB = 9MB
  float* Pg = (float*)d_ws;
  float* Vg = Pg + (size_t)kNCK * 512;
  float* Sg = Vg + (size_t)kNCK * 32;

  pscan_phase1<<<kNCK / 2, 256, 0, stream>>>(Ar, Ai, Xr, Xi, Pg, Vg);
  pscan_phase2<<<kNCH, 64, 0, stream>>>(Pg, Vg, Sg);
  pscan_phase3<<<kNCK / 4, 256, 0, stream>>>(Ar, Ai, Xr, Xi, Sg, (float*)d_out);
}

// Round 6
// 107.505 us; speedup vs baseline: 1.3239x; 1.3239x over previous
//
#include <hip/hip_runtime.h>

#define DEVFN static __device__ __forceinline__

constexpr int kLtot = 1024, kC = 32, kB = 2;
constexpr int kG = 64;                 // chunks per chain
constexpr int kCL = kLtot / kG;        // 16 steps per chunk
constexpr int kNCH = kB * kC;          // 64 chains
constexpr int kNCK = kNCH * kG;        // 4096 chunks

// phase1 per-wave LDS: two 2048B A-slots (ring) + 17x144B pbuf (P bounce rows 0-15, v row 16)
constexpr int kSlotB = 2048;
constexpr int kPbufB = 17 * 144;       // 2448
constexpr int kWaveB = 2 * kSlotB + kPbufB;  // 6544 (16B aligned)

typedef int v2i __attribute__((ext_vector_type(2)));

DEVFN void gload16(const void* g, void* l) {
  __builtin_amdgcn_global_load_lds((const __attribute__((address_space(1))) void*)g,
                                   (__attribute__((address_space(3))) void*)l, 16, 0, 0);
}

// xor-16 via ds_swizzle (DS pipe — overlaps VALU; R3-proven faster than permlane16_swap)
DEVFN float redpair16(float x) {
  return x + __int_as_float(__builtin_amdgcn_ds_swizzle(__float_as_int(x), 0x401F));
}
DEVFN float redpair32(float x) {
#if __has_builtin(__builtin_amdgcn_permlane32_swap)
  v2i r = __builtin_amdgcn_permlane32_swap(__float_as_int(x), __float_as_int(x), false, false);
  return __int_as_float(r.x) + __int_as_float(r.y);
#else
  return x + __shfl_xor(x, 32);
#endif
}
DEVFN float redq(float x) { return redpair32(redpair16(x)); }  // sum over the 4 kq-partners

DEVFN float sel4(float x0, float x1, float x2, float x3, int b) {
  float lo = (b & 1) ? x1 : x0;
  float hi = (b & 1) ? x3 : x2;
  return (b & 2) ? hi : lo;
}

// ---------------- Phase 1: chunk transition P_g + response v_g ----------------
// 1 chunk per wave, 4 waves per block. Lane (kq, ka, kc): partials np[ka+4r][4kc+jj] over
// k in [4kq,4kq+4); reduce over kq via ds_swizzle(xor16) + permlane32; p redistributed via
// per-wave LDS transpose bounce (no explicit drain: same-wave DS ops are in-order, the
// compiler inserts precise lgkmcnt for the read results). P starts as A_0 (step 0 free).
__global__ __launch_bounds__(256, 4) void pscan_phase1(
    const float* __restrict__ Ar, const float* __restrict__ Ai,
    const float* __restrict__ Xr, const float* __restrict__ Xi,
    float* __restrict__ Pg, float* __restrict__ Vg) {
  __shared__ __align__(16) float ldsF[4 * (kWaveB / 4)];
  const int lane = threadIdx.x & 63;
  const int wid = threadIdx.x >> 6;
  const int kq = lane >> 4, ka = (lane >> 2) & 3, kc = lane & 3;
  const int jv = 4 * kc + ka;

  const int ck = blockIdx.x * 4 + wid;
  const int chain = ck >> 6, g = ck & 63;
  const int bb = chain >> 5, cc = chain & 31;
  const int t0 = g * kCL;

  char* ldsW = (char*)ldsF + wid * kWaveB;
  char* pbase = ldsW + 2 * kSlotB;
  const int laneA = ka * 64 + kq * 16;
  const int laneAv = laneA + kc * 256;

  const size_t aBase = ((size_t)(bb * kLtot + t0) * kC + cc) * 256;
  const size_t xBase2 = ((size_t)(bb * kLtot + t0) * kC + cc) * 16;
  const float* arPtr = Ar + aBase + (size_t)lane * 4;
  const float* aiPtr = Ai + aBase + (size_t)lane * 4;
  const float* xrPtr = Xr + xBase2 + jv;
  const float* xiPtr = Xi + xBase2 + jv;

  char* wA = pbase + (ka + 4 * kq) * 144 + kc * 32;           // bounce write row ka+4kq, quad kc
  const char* rA = pbase + (4 * kq) * 144 + kc * 32;          // bounce read rows 4kq+kk
  char* vwA = pbase + 2304 + jv * 8;                          // v write (kq==0 lanes only)
  const char* vrA = pbase + 2304 + kq * 32;                   // v read slice

  float xrP[2], xiP[2];
  auto issueStep = [&](int t) {                               // 4 vmem ops, always
    const size_t ao = (size_t)t * (kC * 256);
    char* sd = ldsW + (t & 1) * kSlotB;
    gload16(arPtr + ao, sd);
    gload16(aiPtr + ao, sd + 1024);
    xrP[t & 1] = xrPtr[(size_t)t * (kC * 16)];
    xiP[t & 1] = xiPtr[(size_t)t * (kC * 16)];
  };

  issueStep(0);
  asm volatile("" ::: "memory");
  issueStep(1);
  asm volatile("" ::: "memory");

  float prk[4][4], pik[4][4];   // p[kk][jj] = P[4kq+kk][4kc+jj]
  float npr[4][4], npi[4][4];   // np[r][jj] = P_new[ka+4r][4kc+jj]
  float vre[4], vim[4];         // v[4kq+kk]
  float vnr = 0.f, vni = 0.f;

  // ---- init: P = A_0, v = x_0 (skips the identity matmul) ----
  asm volatile("s_waitcnt vmcnt(4)" ::: "memory");  // slot 0 resident
  {
    const char* sb = ldsW;
#pragma unroll
    for (int kk = 0; kk < 4; ++kk) {
      const float4 a4 = *(const float4*)(sb + (4 * kq + kk) * 64 + kc * 16);
      const float4 b4 = *(const float4*)(sb + 1024 + (4 * kq + kk) * 64 + kc * 16);
      prk[kk][0] = a4.x; prk[kk][1] = a4.y; prk[kk][2] = a4.z; prk[kk][3] = a4.w;
      pik[kk][0] = b4.x; pik[kk][1] = b4.y; pik[kk][2] = b4.z; pik[kk][3] = b4.w;
    }
    const float* xr0 = Xr + xBase2;
    const float* xi0 = Xi + xBase2;
#pragma unroll
    for (int kk = 0; kk < 4; ++kk) {
      vre[kk] = xr0[4 * kq + kk];
      vim[kk] = xi0[4 * kq + kk];
    }
  }
  asm volatile("s_waitcnt lgkmcnt(0)" ::: "memory");  // slot-0 reads done before re-staging
  issueStep(2);
  asm volatile("" ::: "memory");

  auto stepCompute = [&](int t) {
    const char* sb = ldsW + (t & 1) * kSlotB;
    const char* sbl = sb + laneA;
#pragma unroll
    for (int r = 0; r < 4; ++r) {
      const float4 a4 = *(const float4*)(sbl + r * 256);
      const float4 b4 = *(const float4*)(sbl + 1024 + r * 256);
#pragma unroll
      for (int jj = 0; jj < 4; ++jj) {
        float nr = a4.x * prk[0][jj] - b4.x * pik[0][jj];
        float ni = a4.x * pik[0][jj] + b4.x * prk[0][jj];
        nr += a4.y * prk[1][jj] - b4.y * pik[1][jj];
        ni += a4.y * pik[1][jj] + b4.y * prk[1][jj];
        nr += a4.z * prk[2][jj] - b4.z * pik[2][jj];
        ni += a4.z * pik[2][jj] + b4.z * prk[2][jj];
        nr += a4.w * prk[3][jj] - b4.w * pik[3][jj];
        ni += a4.w * pik[3][jj] + b4.w * prk[3][jj];
        npr[r][jj] = nr; npi[r][jj] = ni;
      }
    }
    {
      const float4 a4 = *(const float4*)(sb + laneAv);
      const float4 b4 = *(const float4*)(sb + laneAv + 1024);
      float pr = a4.x * vre[0] - b4.x * vim[0];
      float pi = a4.x * vim[0] + b4.x * vre[0];
      pr += a4.y * vre[1] - b4.y * vim[1];  pi += a4.y * vim[1] + b4.y * vre[1];
      pr += a4.z * vre[2] - b4.z * vim[2];  pi += a4.z * vim[2] + b4.z * vre[2];
      pr += a4.w * vre[3] - b4.w * vim[3];  pi += a4.w * vim[3] + b4.w * vre[3];
      pr = redq(pr); pi = redq(pi);
      vnr = pr + xrP[t & 1];
      vni = pi + xiP[t & 1];
    }
#pragma unroll
    for (int r = 0; r < 4; ++r)
#pragma unroll
      for (int jj = 0; jj < 4; ++jj) {
        npr[r][jj] = redq(npr[r][jj]);
        npi[r][jj] = redq(npi[r][jj]);
      }
  };

  auto stepBounce = [&]() {
#pragma unroll
    for (int u = 0; u < 2; ++u) {
      float4 w;
      w.x = sel4(npr[0][2 * u], npr[1][2 * u], npr[2][2 * u], npr[3][2 * u], kq);
      w.y = sel4(npi[0][2 * u], npi[1][2 * u], npi[2][2 * u], npi[3][2 * u], kq);
      w.z = sel4(npr[0][2 * u + 1], npr[1][2 * u + 1], npr[2][2 * u + 1], npr[3][2 * u + 1], kq);
      w.w = sel4(npi[0][2 * u + 1], npi[1][2 * u + 1], npi[2][2 * u + 1], npi[3][2 * u + 1], kq);
      *(float4*)(wA + u * 16) = w;
    }
    if (kq == 0) *(float2*)vwA = make_float2(vnr, vni);
    // no explicit lgkmcnt(0): same-wave DS ops are in-order; compiler inserts precise
    // waits before the read RESULTS are consumed, letting read issue overlap write drain.
#pragma unroll
    for (int kk = 0; kk < 4; ++kk) {
      const float4 q0 = *(const float4*)(rA + kk * 144);
      const float4 q1 = *(const float4*)(rA + kk * 144 + 16);
      prk[kk][0] = q0.x; pik[kk][0] = q0.y; prk[kk][1] = q0.z; pik[kk][1] = q0.w;
      prk[kk][2] = q1.x; pik[kk][2] = q1.y; prk[kk][3] = q1.z; pik[kk][3] = q1.w;
    }
    const float4 v0 = *(const float4*)(vrA);
    const float4 v1 = *(const float4*)(vrA + 16);
    vre[0] = v0.x; vim[0] = v0.y; vre[1] = v0.z; vim[1] = v0.w;
    vre[2] = v1.x; vim[2] = v1.y; vre[3] = v1.z; vim[3] = v1.w;
  };

#pragma unroll 2
  for (int t = 1; t < kCL - 2; ++t) {
    asm volatile("s_waitcnt vmcnt(4)" ::: "memory");
    stepCompute(t);
    stepBounce();
    issueStep(t + 2);
  }
  asm volatile("s_waitcnt vmcnt(4)" ::: "memory");
  stepCompute(kCL - 2);
  stepBounce();
  asm volatile("s_waitcnt vmcnt(0)" ::: "memory");
  stepCompute(kCL - 1);

  // store P_g (row-major [i][k] float2) and v_g from the kq==0 lanes
  if (kq == 0) {
    float* pd = Pg + (size_t)ck * 512;
#pragma unroll
    for (int r = 0; r < 4; ++r) {
#pragma unroll
      for (int u = 0; u < 2; ++u) {
        float4 o;
        o.x = npr[r][2 * u];     o.y = npi[r][2 * u];
        o.z = npr[r][2 * u + 1]; o.w = npi[r][2 * u + 1];
        *(float4*)(pd + (ka + 4 * r) * 32 + 8 * kc + 4 * u) = o;
      }
    }
    *(float2*)(Vg + (size_t)ck * 32 + jv * 2) = make_float2(vnr, vni);
  }
}

// ---------------- Phase 2: sequential carry scan (1 chain per wave, 64-lane matvec) ----------
constexpr int kD2 = 4;
__global__ __launch_bounds__(64, 1) void pscan_phase2(
    const float* __restrict__ Pg, const float* __restrict__ Vg, float* __restrict__ Sg) {
  const int lane = threadIdx.x;
  const int kq = lane >> 4, i = lane & 15;
  const int chain = blockIdx.x;

  const float* pB = Pg + (size_t)chain * kG * 512 + (size_t)i * 32 + 8 * kq;
  const float* vB = Vg + (size_t)chain * kG * 32 + 2 * i;
  float* sB = Sg + (size_t)chain * kG * 32 + 2 * i;

  float4 bP0[kD2], bP1[kD2]; float2 bV[kD2];
#pragma unroll
  for (int d = 0; d < kD2; ++d) {
    bP0[d] = *(const float4*)(pB + (size_t)d * 512);
    bP1[d] = *(const float4*)(pB + (size_t)d * 512 + 4);
    bV[d] = *(const float2*)(vB + (size_t)d * 32);
  }

  float ykr[4] = {0, 0, 0, 0}, yki[4] = {0, 0, 0, 0};  // y[4kq+kk]
  float ynr = 0.f, yni = 0.f;                          // own y[i]

  for (int gg = 0; gg < kG; gg += kD2) {
#pragma unroll
    for (int d = 0; d < kD2; ++d) {
      if (kq == 0) *(float2*)(sB + (size_t)(gg + d) * 32) = make_float2(ynr, yni);  // S_{g-1}
      const float4 p0 = bP0[d], p1 = bP1[d];
      const float2 vv = bV[d];
      const int gn = gg + d + kD2;
      if (gn < kG) {
        bP0[d] = *(const float4*)(pB + (size_t)gn * 512);
        bP1[d] = *(const float4*)(pB + (size_t)gn * 512 + 4);
        bV[d] = *(const float2*)(vB + (size_t)gn * 32);
      }
      float tr = p0.x * ykr[0] - p0.y * yki[0] + p0.z * ykr[1] - p0.w * yki[1]
               + p1.x * ykr[2] - p1.y * yki[2] + p1.z * ykr[3] - p1.w * yki[3];
      float ti = p0.x * yki[0] + p0.y * ykr[0] + p0.z * yki[1] + p0.w * ykr[1]
               + p1.x * yki[2] + p1.y * ykr[2] + p1.z * yki[3] + p1.w * ykr[3];
      tr = redq(tr); ti = redq(ti);
      ynr = tr + vv.x;
      yni = ti + vv.y;
#pragma unroll
      for (int kk = 0; kk < 4; ++kk) {
        const int src = (lane & 48) | (4 * kq + kk);
        ykr[kk] = __shfl(ynr, src);
        yki[kk] = __shfl(yni, src);
      }
    }
  }
}

// ---------------- Phase 3: replay chunks from carries (64-lane matvec, high occupancy) ----------
__global__ __launch_bounds__(256, 4) void pscan_phase3(
    const float* __restrict__ Ar, const float* __restrict__ Ai,
    const float* __restrict__ Xr, const float* __restrict__ Xi,
    const float* __restrict__ Sg, float* __restrict__ out) {
  const int lane = threadIdx.x & 63;
  const int wid = threadIdx.x >> 6;
  const int kq = lane >> 4, i = lane & 15;
  const int ck = blockIdx.x * 4 + wid;
  const int chain = ck >> 6, g = ck & 63;
  const int bb = chain >> 5, cc = chain & 31;
  const int t0 = g * kCL;

  const size_t aBase = ((size_t)(bb * kLtot + t0) * kC + cc) * 256 + (size_t)i * 16 + 4 * kq;
  const size_t xBase = ((size_t)(bb * kLtot + t0) * kC + cc) * 16 + i;
  const size_t aStep = (size_t)kC * 256, xStep = (size_t)kC * 16;
  float* outB = out + ((size_t)(bb * kLtot + t0) * kC + cc) * 32 + 2 * i;

  float ynr, yni, ykr[4], yki[4];
  {
    const float2 s = *(const float2*)(Sg + (size_t)ck * 32 + 2 * i);
    ynr = s.x; yni = s.y;
  }
#pragma unroll
  for (int kk = 0; kk < 4; ++kk) {
    const int src = (lane & 48) | (4 * kq + kk);
    ykr[kk] = __shfl(ynr, src);
    yki[kk] = __shfl(yni, src);
  }

  float4 aR[2], aI[2]; float2 xx[2];
  auto loadT = [&](int t, int s) {
    aR[s] = *(const float4*)(Ar + aBase + (size_t)t * aStep);
    aI[s] = *(const float4*)(Ai + aBase + (size_t)t * aStep);
    xx[s].x = Xr[xBase + (size_t)t * xStep];
    xx[s].y = Xi[xBase + (size_t)t * xStep];
  };
  loadT(0, 0);
  loadT(1, 1);

  for (int t = 0; t < kCL; ++t) {
    const int s = t & 1;
    const float4 a4 = aR[s], b4 = aI[s];
    const float2 xv = xx[s];
    float tr = a4.x * ykr[0] - b4.x * yki[0] + a4.y * ykr[1] - b4.y * yki[1]
             + a4.z * ykr[2] - b4.z * yki[2] + a4.w * ykr[3] - b4.w * yki[3];
    float ti = a4.x * yki[0] + b4.x * ykr[0] + a4.y * yki[1] + b4.y * ykr[1]
             + a4.z * yki[2] + b4.z * ykr[2] + a4.w * yki[3] + b4.w * ykr[3];
    tr = redq(tr); ti = redq(ti);
    ynr = tr + xv.x;
    yni = ti + xv.y;
    if (kq == 0) *(float2*)(outB + (size_t)t * (kC * 32)) = make_float2(ynr, yni);
    const int tn = t + 2;
    if (tn < kCL) loadT(tn, s);
#pragma unroll
    for (int kk = 0; kk < 4; ++kk) {
      const int src = (lane & 48) | (4 * kq + kk);
      ykr[kk] = __shfl(ynr, src);
      yki[kk] = __shfl(yni, src);
    }
  }
}

extern "C" void kernel_launch(void* const* d_in, const int* in_sizes, int n_in,
                              void* d_out, int out_size, void* d_ws, size_t ws_size,
                              hipStream_t stream) {
  const float* Ar = (const float*)d_in[0];
  const float* Ai = (const float*)d_in[1];
  const float* Xr = (const float*)d_in[2];
  const float* Xi = (const float*)d_in[3];
  // Workspace: Pg 8MB + Vg 512KB + Sg 512KB = 9MB
  float* Pg = (float*)d_ws;
  float* Vg = Pg + (size_t)kNCK * 512;
  float* Sg = Vg + (size_t)kNCK * 32;

  pscan_phase1<<<kNCK / 4, 256, 0, stream>>>(Ar, Ai, Xr, Xi, Pg, Vg);
  pscan_phase2<<<kNCH, 64, 0, stream>>>(Pg, Vg, Sg);
  pscan_phase3<<<kNCK / 4, 256, 0, stream>>>(Ar, Ai, Xr, Xi, Sg, (float*)d_out);
}